// Round 11
// baseline (190.925 us; speedup 1.0000x reference)
//
#include <hip/hip_runtime.h>
#include <hip/hip_cooperative_groups.h>

namespace cg = cooperative_groups;

// zs: (V=2, B=8192, F=4096) fp32 row-major -> N = 16384 rows, F = 4096 contiguous.
// loss = mean_f[ (s2c^2 - s4c) / (N-1)^3 ] via raw moments S1..S4 per feature.
// R11 = R8 structure fused into ONE cooperative kernel (grid.sync replaces the
// pass1->pass2 kernel boundary; ticket finisher unchanged).
constexpr int F_DIM = 4096;
constexpr int TPB = 256;
constexpr int NCHUNK = 64;        // row-chunks -> partials = 64*4096*16B = 4 MB
constexpr int FCHUNK = 16;        // feature chunks of 64 float4-cols
constexpr int NBLK = FCHUNK * NCHUNK;   // 1024 blocks = 4/CU (resident-safe)

__global__ void __launch_bounds__(TPB) cov_fused(
    const float* __restrict__ zs, float4* __restrict__ part,
    double* __restrict__ blk, unsigned int* __restrict__ ticket,
    float* __restrict__ out, int rows_per_chunk, int N, double scale) {
  const int b = blockIdx.x;
  // Reset the finisher ticket; grid.sync()'s fence orders it before phase B.
  if (b == 0 && threadIdx.x == 0)
    __hip_atomic_store(ticket, 0u, __ATOMIC_RELAXED, __HIP_MEMORY_SCOPE_AGENT);

  // ---------------- Phase A: streaming raw moments (R8 pass1) --------------
  {
    const int fc = b & (FCHUNK - 1);         // 0..15 feature chunk
    const int rc = b >> 4;                   // 0..63 row chunk
    const int col = threadIdx.x & 63;        // float4 col within strip
    const int sr = threadIdx.x >> 6;         // subrow group 0..3
    const int f4 = fc * 64 + col;            // global float4 column [0,1024)
    const int rows_per_sub = rows_per_chunk >> 2;      // 64
    const size_t row0 =
        (size_t)rc * rows_per_chunk + (size_t)sr * rows_per_sub;
    const float4* __restrict__ src =
        reinterpret_cast<const float4*>(zs) + row0 * (F_DIM / 4) + f4;
    const size_t rstride = F_DIM / 4;

    float s1[4] = {0.f, 0.f, 0.f, 0.f};
    float s2[4] = {0.f, 0.f, 0.f, 0.f};
    float s3[4] = {0.f, 0.f, 0.f, 0.f};
    float s4[4] = {0.f, 0.f, 0.f, 0.f};

    int r = 0;
    for (; r + 4 <= rows_per_sub; r += 4) {  // 16 iters, 4 dwordx4 in flight
      float4 zz[4];
#pragma unroll
      for (int u = 0; u < 4; ++u) zz[u] = src[(size_t)(r + u) * rstride];
#pragma unroll
      for (int u = 0; u < 4; ++u) {
        float v[4] = {zz[u].x, zz[u].y, zz[u].z, zz[u].w};
#pragma unroll
        for (int j = 0; j < 4; ++j) {
          float x = v[j];
          float x2 = x * x;
          s1[j] += x;
          s2[j] = fmaf(x, x, s2[j]);
          s3[j] = fmaf(x2, x, s3[j]);
          s4[j] = fmaf(x2, x2, s4[j]);
        }
      }
    }
    for (; r < rows_per_sub; ++r) {          // tail (unused: 64 % 4 == 0)
      float4 z = src[(size_t)r * rstride];
      float v[4] = {z.x, z.y, z.z, z.w};
#pragma unroll
      for (int j = 0; j < 4; ++j) {
        float x = v[j];
        float x2 = x * x;
        s1[j] += x;
        s2[j] = fmaf(x, x, s2[j]);
        s3[j] = fmaf(x2, x, s3[j]);
        s4[j] = fmaf(x2, x2, s4[j]);
      }
    }

    // LDS reduce across the 4 subrow groups; pad breaks the 64B-stride banks.
    __shared__ float4 lds[4][64][5];
#pragma unroll
    for (int j = 0; j < 4; ++j)
      lds[sr][col][j] = make_float4(s1[j], s2[j], s3[j], s4[j]);
    __syncthreads();

    const int wcol = threadIdx.x >> 2;       // 0..63
    const int wj = threadIdx.x & 3;          // 0..3
    float4 a = lds[0][wcol][wj];
    float4 bb = lds[1][wcol][wj];
    float4 c = lds[2][wcol][wj];
    float4 d = lds[3][wcol][wj];
    float4 sum = make_float4(a.x + bb.x + c.x + d.x, a.y + bb.y + c.y + d.y,
                             a.z + bb.z + c.z + d.z, a.w + bb.w + c.w + d.w);
    part[(size_t)rc * F_DIM + (size_t)fc * 256 + threadIdx.x] = sum;
  }

  // Kernel-boundary replacement: grid-wide barrier + device-scope fence.
  cg::this_grid().sync();

  // ---------------- Phase B: fp64 combine + loss + finisher (R8 pass2) -----
  if (b < F_DIM / 16) {                      // 256 blocks participate
    const int fi = threadIdx.x & 15;
    const int ci = threadIdx.x >> 4;
    const int f = b * 16 + fi;

    double S[4] = {0.0, 0.0, 0.0, 0.0};
    for (int c = ci; c < NCHUNK; c += 16) {
      float4 p = part[(size_t)c * F_DIM + f];
      S[0] += (double)p.x;
      S[1] += (double)p.y;
      S[2] += (double)p.z;
      S[3] += (double)p.w;
    }

    __shared__ double red[16][16][4];
#pragma unroll
    for (int m = 0; m < 4; ++m) red[ci][fi][m] = S[m];
    __syncthreads();

    __shared__ double loss_lds[16];
    if (threadIdx.x < 16) {                  // one thread per feature
      const int ff = threadIdx.x;
      double S1 = 0.0, S2 = 0.0, S3 = 0.0, S4 = 0.0;
      for (int c = 0; c < 16; ++c) {
        S1 += red[c][ff][0];
        S2 += red[c][ff][1];
        S3 += red[c][ff][2];
        S4 += red[c][ff][3];
      }
      const double n = (double)N;
      const double m = S1 / n;
      const double m2 = m * m;
      const double s2c = S2 - n * m2;
      const double s4c = S4 - 4.0 * m * S3 + 6.0 * m2 * S2 - 3.0 * n * m2 * m2;
      loss_lds[ff] = s2c * s2c - s4c;
    }
    __syncthreads();

    __shared__ unsigned int is_last;
    if (threadIdx.x == 0) {
      double s = 0.0;
      for (int i = 0; i < 16; ++i) s += loss_lds[i];
      __hip_atomic_store(&blk[b], s, __ATOMIC_RELEASE,
                         __HIP_MEMORY_SCOPE_AGENT);
      unsigned int t = __hip_atomic_fetch_add(ticket, 1u, __ATOMIC_ACQ_REL,
                                              __HIP_MEMORY_SCOPE_AGENT);
      is_last = (t == (unsigned int)(F_DIM / 16 - 1)) ? 1u : 0u;
    }
    __syncthreads();

    if (is_last) {
      __shared__ double fin[TPB];
      double v = 0.0;
      if (threadIdx.x < F_DIM / 16)          // parallel acquire loads (4 waves)
        v = __hip_atomic_load(&blk[threadIdx.x], __ATOMIC_ACQUIRE,
                              __HIP_MEMORY_SCOPE_AGENT);
      fin[threadIdx.x] = v;
      __syncthreads();
      for (int s = TPB / 2; s > 0; s >>= 1) {  // fixed-order tree
        if (threadIdx.x < s) fin[threadIdx.x] += fin[threadIdx.x + s];
        __syncthreads();
      }
      if (threadIdx.x == 0) out[0] = (float)(fin[0] * scale);
    }
  }
}

extern "C" void kernel_launch(void* const* d_in, const int* in_sizes, int n_in,
                              void* d_out, int out_size, void* d_ws, size_t ws_size,
                              hipStream_t stream) {
  const float* zs = (const float*)d_in[0];
  float* out = (float*)d_out;
  const size_t total = (size_t)in_sizes[0];
  int N = (int)(total / F_DIM);              // 16384 rows
  int rows_per_chunk = N / NCHUNK;           // 256 (64 rows per thread)

  float4* part = (float4*)d_ws;              // 4 MB
  char* after_part = (char*)d_ws + (size_t)NCHUNK * F_DIM * sizeof(float4);
  double* blk = (double*)after_part;         // 2 KB
  unsigned int* ticket = (unsigned int*)(after_part + 256 * sizeof(double));

  const double nm1 = (double)(N - 1);
  double scale = 1.0 / (nm1 * nm1 * nm1 * (double)F_DIM);

  void* args[] = {(void*)&zs,   (void*)&part,  (void*)&blk, (void*)&ticket,
                  (void*)&out,  (void*)&rows_per_chunk, (void*)&N,
                  (void*)&scale};
  hipLaunchCooperativeKernel((const void*)cov_fused, dim3(NBLK), dim3(TPB),
                             args, 0, stream);
}

// Round 14
// 49.571 us; speedup vs baseline: 3.8515x; 3.8515x over previous
//
#include <hip/hip_runtime.h>

// zs: (V=2, B=8192, F=4096) fp32 row-major -> N = 16384 rows, F = 4096 contiguous.
// loss = mean_f[ (s2c^2 - s4c) / (N-1)^3 ] via raw moments S1..S4 per feature.
//
// R14: race-free FINAL. R13 (in-kernel ticket finisher) intermittently
// diverged on graph replays -- cross-XCD visibility of the per-block results
// is not dependable even via agent-scope acquire/release chains (G16; R12/R13
// lessons). All cross-block communication now crosses kernel boundaries:
//   pass1: streaming raw moments (best measured shape, ~5.8 TB/s)
//   pass2: fp64 combine + per-block loss partial (256 blocks)
//   pass3: one block, fixed-order tree reduce + scale
// No atomics, no tickets, no memsets. Deterministic bit-identical output.
constexpr int F_DIM = 4096;
constexpr int TPB = 256;
constexpr int NCHUNK = 64;        // row-chunks -> partials = 64*4096*16B = 4 MB
constexpr int FCHUNK = 16;        // feature chunks of 64 float4-cols (256 features)

// ---------------- Pass 1: streaming raw moments + in-block subrow reduce ----
// grid = (16, 64). Block (fc, rc): float4 cols [fc*64, fc*64+64), rows
// [rc*256, rc*256+256). Thread = (sr = t>>6 in 0..3, col = t&63): sr owns 64
// consecutive rows; each wave load = 64 lanes * 16B = 1 KB contiguous.
// After accumulation, LDS-reduce the 4 subrows -> block writes 4 KB.
__global__ void __launch_bounds__(TPB) cov_pass1(
    const float* __restrict__ zs, float4* __restrict__ part,
    int rows_per_chunk) {
  const int col = threadIdx.x & 63;          // float4 col within block strip
  const int sr = threadIdx.x >> 6;           // subrow group 0..3
  const int fc = blockIdx.x;                 // 0..15
  const int rc = blockIdx.y;                 // 0..63
  const int f4 = fc * 64 + col;              // global float4 column [0,1024)
  const int rows_per_sub = rows_per_chunk >> 2;        // 64
  const size_t row0 = (size_t)rc * rows_per_chunk + (size_t)sr * rows_per_sub;
  const float4* __restrict__ src =
      reinterpret_cast<const float4*>(zs) + row0 * (F_DIM / 4) + f4;
  const size_t rstride = F_DIM / 4;

  float s1[4] = {0.f, 0.f, 0.f, 0.f};
  float s2[4] = {0.f, 0.f, 0.f, 0.f};
  float s3[4] = {0.f, 0.f, 0.f, 0.f};
  float s4[4] = {0.f, 0.f, 0.f, 0.f};

  int r = 0;
  for (; r + 4 <= rows_per_sub; r += 4) {    // 16 iters, 4 dwordx4 in flight
    float4 zz[4];
#pragma unroll
    for (int u = 0; u < 4; ++u) zz[u] = src[(size_t)(r + u) * rstride];
#pragma unroll
    for (int u = 0; u < 4; ++u) {
      float v[4] = {zz[u].x, zz[u].y, zz[u].z, zz[u].w};
#pragma unroll
      for (int j = 0; j < 4; ++j) {
        float x = v[j];
        float x2 = x * x;
        s1[j] += x;
        s2[j] = fmaf(x, x, s2[j]);
        s3[j] = fmaf(x2, x, s3[j]);
        s4[j] = fmaf(x2, x2, s4[j]);
      }
    }
  }
  for (; r < rows_per_sub; ++r) {            // tail (unused: 64 % 4 == 0)
    float4 z = src[(size_t)r * rstride];
    float v[4] = {z.x, z.y, z.z, z.w};
#pragma unroll
    for (int j = 0; j < 4; ++j) {
      float x = v[j];
      float x2 = x * x;
      s1[j] += x;
      s2[j] = fmaf(x, x, s2[j]);
      s3[j] = fmaf(x2, x, s3[j]);
      s4[j] = fmaf(x2, x2, s4[j]);
    }
  }

  // LDS reduce across the 4 subrow groups. [4][64][5]: 5th-slot pad breaks
  // the 64B stride that would otherwise put all lanes on 2 banks.
  __shared__ float4 lds[4][64][5];
#pragma unroll
  for (int j = 0; j < 4; ++j)
    lds[sr][col][j] = make_float4(s1[j], s2[j], s3[j], s4[j]);
  __syncthreads();

  // Writer: thread t emits moment-float4 of block-feature t (coalesced 4 KB).
  {
    const int wcol = threadIdx.x >> 2;       // 0..63
    const int wj = threadIdx.x & 3;          // 0..3
    float4 a = lds[0][wcol][wj];
    float4 b = lds[1][wcol][wj];
    float4 c = lds[2][wcol][wj];
    float4 d = lds[3][wcol][wj];
    float4 sum = make_float4(a.x + b.x + c.x + d.x, a.y + b.y + c.y + d.y,
                             a.z + b.z + c.z + d.z, a.w + b.w + c.w + d.w);
    part[(size_t)rc * F_DIM + (size_t)fc * 256 + threadIdx.x] = sum;
  }
}

// ---------------- Pass 2: fp64 combine + per-block loss partial ------------
// 256 blocks; block b owns features [b*16, b*16+16). fi = t&15, ci = t>>4
// (16 chunk-lanes per feature, 4 iterations over 64 chunks; coalesced 256B
// segments). Block writes ONE double partial; no cross-block communication.
__global__ void __launch_bounds__(TPB) cov_pass2(
    const float4* __restrict__ part, double* __restrict__ blk, int nchunk,
    int N) {
  const int fi = threadIdx.x & 15;
  const int ci = threadIdx.x >> 4;
  const int f = blockIdx.x * 16 + fi;

  double S[4] = {0.0, 0.0, 0.0, 0.0};
  for (int c = ci; c < nchunk; c += 16) {
    float4 p = part[(size_t)c * F_DIM + f];
    S[0] += (double)p.x;
    S[1] += (double)p.y;
    S[2] += (double)p.z;
    S[3] += (double)p.w;
  }

  __shared__ double red[16][16][4];
#pragma unroll
  for (int m = 0; m < 4; ++m) red[ci][fi][m] = S[m];
  __syncthreads();

  __shared__ double loss_lds[16];
  if (threadIdx.x < 16) {                    // one thread per feature
    const int ff = threadIdx.x;
    double S1 = 0.0, S2 = 0.0, S3 = 0.0, S4 = 0.0;
    for (int c = 0; c < 16; ++c) {
      S1 += red[c][ff][0];
      S2 += red[c][ff][1];
      S3 += red[c][ff][2];
      S4 += red[c][ff][3];
    }
    const double n = (double)N;
    const double m = S1 / n;
    const double m2 = m * m;
    const double s2c = S2 - n * m2;
    const double s4c = S4 - 4.0 * m * S3 + 6.0 * m2 * S2 - 3.0 * n * m2 * m2;
    loss_lds[ff] = s2c * s2c - s4c;
  }
  __syncthreads();

  if (threadIdx.x == 0) {
    double s = 0.0;
    for (int i = 0; i < 16; ++i) s += loss_lds[i];   // fixed order
    blk[blockIdx.x] = s;
  }
}

// ---------------- Pass 3: one block, fixed-order tree + scale --------------
__global__ void __launch_bounds__(TPB) cov_pass3(
    const double* __restrict__ blk, int nblk, double scale,
    float* __restrict__ out) {
  __shared__ double fin[TPB];
  double v = (threadIdx.x < nblk) ? blk[threadIdx.x] : 0.0;
  for (int i = threadIdx.x + TPB; i < nblk; i += TPB) v += blk[i];
  fin[threadIdx.x] = v;
  __syncthreads();
  for (int s = TPB / 2; s > 0; s >>= 1) {    // fixed-order tree
    if (threadIdx.x < s) fin[threadIdx.x] += fin[threadIdx.x + s];
    __syncthreads();
  }
  if (threadIdx.x == 0) out[0] = (float)(fin[0] * scale);
}

extern "C" void kernel_launch(void* const* d_in, const int* in_sizes, int n_in,
                              void* d_out, int out_size, void* d_ws, size_t ws_size,
                              hipStream_t stream) {
  const float* zs = (const float*)d_in[0];
  float* out = (float*)d_out;
  const size_t total = (size_t)in_sizes[0];
  const int N = (int)(total / F_DIM);        // 16384 rows

  const int nchunk = NCHUNK;                 // 64
  const int rows_per_chunk = N / nchunk;     // 256 (subrow = 64 rows/thread)

  float4* part = (float4*)d_ws;              // 4 MB
  double* blk =
      (double*)((char*)d_ws + (size_t)nchunk * F_DIM * sizeof(float4));

  dim3 g1(FCHUNK, nchunk);                   // (16, 64) = 1024 blocks
  cov_pass1<<<g1, TPB, 0, stream>>>(zs, part, rows_per_chunk);

  const int nblk2 = F_DIM / 16;              // 256 blocks
  cov_pass2<<<nblk2, TPB, 0, stream>>>(part, blk, nchunk, N);

  const double nm1 = (double)(N - 1);
  const double scale = 1.0 / (nm1 * nm1 * nm1 * (double)F_DIM);
  cov_pass3<<<1, TPB, 0, stream>>>(blk, nblk2, scale, out);
}